// Round 11
// baseline (98.976 us; speedup 1.0000x reference)
//
#include <hip/hip_runtime.h>
#include <stdint.h>

// Problem: B,T,C = 2,768,64; N_HEAD=64 -> head_dim=1; fp32 buffers.
// R10 post-mortem: 4 different attn structures all land 22-27 us vs 4-8 us
// issue models -> model is missing the real wall; no counters exist for any
// non-spilled attn (40-us harness fills flood rocprof top-5).
// R11 = PROBE: R10 attn unchanged, but inner j-loop repeated rep=3 times
// (memory-clobber per rep; accumulators re-zeroed; stage/epilogue once;
// output identical). attn dispatch ~60 us -> visible in top-5 WITH counters.
// Readout: VALUBusy>60% => issue-bound (R12: factorized-exp, fewer ops/pair);
//          VALUBusy<=35% => latency/occupancy (R12: 24 waves/CU + more ILP).
constexpr int Tc = 768;
constexpr int Hc = 64;
constexpr int Bc = 2;
constexpr float LOG2E = 1.44269504088896f;
constexpr size_t SLAB = (size_t)Bc * Hc * Tc;   // 98304 floats per slab

typedef float v2f __attribute__((ext_vector_type(2)));
typedef float v4f __attribute__((ext_vector_type(4)));

// ---------------------------------------------------------------------------
// Kernel 1: projection into transposed slabs (measured ~3 us, R7).
// ---------------------------------------------------------------------------
__global__ __launch_bounds__(256) void proj_kernel(
    const float* __restrict__ x, const float* __restrict__ W,
    const float* __restrict__ vtmp, const float* __restrict__ ptmp,
    float* __restrict__ qs, float* __restrict__ ks, float* __restrict__ vs)
{
    const int lane = threadIdx.x & 63;
    const int w    = __builtin_amdgcn_readfirstlane(threadIdx.x >> 6);
    const int g    = blockIdx.x * 64 + lane;     // global row in [0,1536)
    const int bh0  = (g / Tc) * Hc;              // b*64 (64 | 768: no straddle)
    const int t    = g % Tc;
    const int h    = blockIdx.y * 4 + w;         // wave-uniform head

    float xr[64];
    const v4f* xp = (const v4f*)(x + (size_t)g * 64);
#pragma unroll
    for (int c = 0; c < 16; ++c) ((v4f*)xr)[c] = xp[c];

    const float* __restrict__ wq = W + h * 64;
    const float* __restrict__ wk = W + (64 + h) * 64;
    float aq = 0.f, ak = 0.f;
#pragma unroll
    for (int c = 0; c < 64; ++c) {               // constant indices only
        aq = fmaf(xr[c], wq[c], aq);
        ak = fmaf(xr[c], wk[c], ak);
    }
    const size_t o = (size_t)(bh0 + h) * Tc + t;   // lane-coalesced
    qs[o] = aq * LOG2E;
    ks[o] = ak;
    vs[o] = x[(size_t)g * 64 + h] * vtmp[h] * ptmp[h];   // global reload, not xr[h]
}

// ---------------------------------------------------------------------------
// Kernel 2: attention (R10 structure, rep-probe). Block = (rt:128 rows, h, b),
// 4 waves = 4 j-quarters; lane owns row pair (i, i+64) in v2f; per j: one
// broadcast ds_read_b64 + packed math + 2 exp. Wave-uniform ALiBi chunk skip.
// grid (6,64,2) = 3 blocks/CU, 12 waves/CU.
// ---------------------------------------------------------------------------
__global__ __launch_bounds__(256, 3) void attn_kernel(
    const float* __restrict__ qs, const float* __restrict__ ks,
    const float* __restrict__ vs, float* __restrict__ out, int rep)
{
    const int tid  = threadIdx.x;
    const int lane = tid & 63;
    const int w    = __builtin_amdgcn_readfirstlane(tid >> 6);
    const int rt   = blockIdx.x;   // 0..5 (128-row tile)
    const int h    = blockIdx.y;
    const int b    = blockIdx.z;
    const int bh   = b * Hc + h;

    __shared__ v2f  kv[Tc];                        // interleaved {k[t], v[t]}
    __shared__ float psum[4][128], pacc[4][128];

    const float* __restrict__ kp = ks + (size_t)bh * Tc;
    const float* __restrict__ vp = vs + (size_t)bh * Tc;
    const float* __restrict__ qp = qs + (size_t)bh * Tc;

    // ---- stage k,v into LDS (once) ----
#pragma unroll
    for (int r = 0; r < 3; ++r) {
        const int t = tid + 256 * r;
        v2f e; e.x = kp[t]; e.y = vp[t];
        kv[t] = e;
    }

    const int i0 = rt * 128 + lane;                // row pair (i0, i0+64)
    v2f q2; q2.x = qp[i0]; q2.y = qp[i0 + 64];     // log2e folded
    const float slope2 = exp2f(-0.125f * (float)(h + 1)) * LOG2E;

    v2f cu2[16];
#pragma unroll
    for (int u = 0; u < 16; ++u) { cu2[u].x = slope2 * (float)u; cu2[u].y = cu2[u].x; }

    __syncthreads();

    const int j0 = w * (Tc / 4);
    int c0 = 0;
    {
        const int jskip = rt * 128 - (int)(28.f / slope2);  // bias < 2^-28 beyond
        if (jskip > j0) {
            c0 = (jskip - j0) >> 4;
            if (c0 > 12) c0 = 12;
        }
    }

    const v2f* __restrict__ kvq = &kv[j0];
    v2f sum2, acc2;
    // ======== PROBE: repeat the inner loop rep times (same result) ========
    for (int it = 0; it < rep; ++it) {
        asm volatile("" ::: "memory");             // force real LDS re-reads
        sum2 = (v2f){0.f, 0.f};
        acc2 = (v2f){0.f, 0.f};
        for (int c = c0; c < 12; ++c) {            // 16 j per chunk
            v2f mb2;
            mb2.x = slope2 * (float)(j0 + 16 * c - i0);
            mb2.y = slope2 * (float)(j0 + 16 * c - (i0 + 64));
#pragma unroll
            for (int u = 0; u < 16; ++u) {
                v2f kvj = kvq[16 * c + u];         // broadcast ds_read_b64
                v2f t2  = mb2 + cu2[u];
                v2f bias;
                bias.x = fminf(t2.x, 0.f);
                bias.y = fminf(t2.y, 0.f);
                v2f kk = {kvj.x, kvj.x};
                v2f sc = q2 * kk + bias;
                v2f e;
                e.x = __builtin_amdgcn_exp2f(sc.x);
                e.y = __builtin_amdgcn_exp2f(sc.y);
                sum2 += e;
                v2f vv = {kvj.y, kvj.y};
                acc2 = e * vv + acc2;
            }
        }
    }
    // ======================================================================
    psum[w][lane]      = sum2.x;
    psum[w][lane + 64] = sum2.y;
    pacc[w][lane]      = acc2.x;
    pacc[w][lane + 64] = acc2.y;
    __syncthreads();

    if (tid < 128) {
        float s = psum[0][tid] + psum[1][tid] + psum[2][tid] + psum[3][tid];
        float a = pacc[0][tid] + pacc[1][tid] + pacc[2][tid] + pacc[3][tid];
        out[((size_t)(b * Tc + rt * 128 + tid)) * 64 + h] =
            a * __builtin_amdgcn_rcpf(s);
    }
}

extern "C" void kernel_launch(void* const* d_in, const int* in_sizes, int n_in,
                              void* d_out, int out_size, void* d_ws, size_t ws_size,
                              hipStream_t stream) {
    const float* x    = (const float*)d_in[0];
    const float* W    = (const float*)d_in[1];
    const float* vtmp = (const float*)d_in[2];
    const float* ptmp = (const float*)d_in[3];
    float* out = (float*)d_out;

    float* qsl = (float*)d_ws;
    float* ksl = qsl + SLAB;
    float* vsl = ksl + SLAB;

    proj_kernel<<<dim3(24, 16), 256, 0, stream>>>(x, W, vtmp, ptmp, qsl, ksl, vsl);
    // rep=3 probe: lifts attn (~22us) above the ~40us fill cutoff so it
    // appears in rocprof top-5 with counters. Output identical to rep=1.
    attn_kernel<<<dim3(6, Hc, Bc), 256, 0, stream>>>(qsl, ksl, vsl, out, 3);
}

// Round 12
// 75.776 us; speedup vs baseline: 1.3062x; 1.3062x over previous
//
#include <hip/hip_runtime.h>
#include <stdint.h>

// Problem: B,T,C = 2,768,64; N_HEAD=64 -> head_dim=1; fp32 buffers.
// R11 probe: attn inner loop = ~8 us VALU-issue, ~45% stall at 12 waves/CU,
// VALUBusy 57%, rep=1 attn dispatch ~14.5 us (+~7 us per-kernel dur gap).
// R12: pack 2 ADJACENT J's per v2f op (not 2 rows) -> single-row lanes keep
// 64-row tiles => grid (12,64,2) = 6 blocks/CU = 24 waves/CU (R9 occupancy +
// R10 packing). Split LDS k/v arrays so j-pairs are register-adjacent for
// v_pk_* (no extract moves). Wave-uniform chunk classes: future (bias=0,
// no add/min), past (no min), mixed (full path); ALiBi distant-past skip.
constexpr int Tc = 768;
constexpr int Hc = 64;
constexpr int Bc = 2;
constexpr float LOG2E = 1.44269504088896f;
constexpr size_t SLAB = (size_t)Bc * Hc * Tc;   // 98304 floats per slab

typedef float v2f __attribute__((ext_vector_type(2)));
typedef float v4f __attribute__((ext_vector_type(4)));

// ---------------------------------------------------------------------------
// Kernel 1: projection into transposed slabs (measured ~3 us, R7).
// ---------------------------------------------------------------------------
__global__ __launch_bounds__(256) void proj_kernel(
    const float* __restrict__ x, const float* __restrict__ W,
    const float* __restrict__ vtmp, const float* __restrict__ ptmp,
    float* __restrict__ qs, float* __restrict__ ks, float* __restrict__ vs)
{
    const int lane = threadIdx.x & 63;
    const int w    = __builtin_amdgcn_readfirstlane(threadIdx.x >> 6);
    const int g    = blockIdx.x * 64 + lane;     // global row in [0,1536)
    const int bh0  = (g / Tc) * Hc;              // b*64 (64 | 768: no straddle)
    const int t    = g % Tc;
    const int h    = blockIdx.y * 4 + w;         // wave-uniform head

    float xr[64];
    const v4f* xp = (const v4f*)(x + (size_t)g * 64);
#pragma unroll
    for (int c = 0; c < 16; ++c) ((v4f*)xr)[c] = xp[c];

    const float* __restrict__ wq = W + h * 64;
    const float* __restrict__ wk = W + (64 + h) * 64;
    float aq = 0.f, ak = 0.f;
#pragma unroll
    for (int c = 0; c < 64; ++c) {               // constant indices only
        aq = fmaf(xr[c], wq[c], aq);
        ak = fmaf(xr[c], wk[c], ak);
    }
    const size_t o = (size_t)(bh0 + h) * Tc + t;   // lane-coalesced
    qs[o] = aq * LOG2E;
    ks[o] = ak;
    vs[o] = x[(size_t)g * 64 + h] * vtmp[h] * ptmp[h];   // global reload, not xr[h]
}

// ---------------------------------------------------------------------------
// Kernel 2: attention. Block = (rt: 64 rows, h, b); lane = row; 4 waves = 4
// j-quarters (192 j). Inner iter = 2 adjacent j via v2f: 2x ds_read_b64
// broadcast (k-pair, v-pair) + pk math + 2 exp2. Chunk classes (all wave-
// uniform): [skip] bias < 2^-28 | past: bias=t2 (no min) | mixed: full |
// future: bias=0 (no add/min). grid (12,64,2) = 1536 = 6 blocks/CU.
// ---------------------------------------------------------------------------
__global__ __launch_bounds__(256, 6) void attn_kernel(
    const float* __restrict__ qs, const float* __restrict__ ks,
    const float* __restrict__ vs, float* __restrict__ out)
{
    const int tid  = threadIdx.x;
    const int lane = tid & 63;
    const int w    = __builtin_amdgcn_readfirstlane(tid >> 6);
    const int rt   = blockIdx.x;   // 0..11 (64-row tile)
    const int h    = blockIdx.y;
    const int b    = blockIdx.z;
    const int bh   = b * Hc + h;

    __shared__ float kl[Tc];                 // k[t]
    __shared__ float vl[Tc];                 // v[t] (vtmp*ptmp folded)
    __shared__ float psum[4][64], pacc[4][64];

    const float* __restrict__ kp = ks + (size_t)bh * Tc;
    const float* __restrict__ vp = vs + (size_t)bh * Tc;

    // ---- stage k,v into LDS (coalesced, 3 t per thread) ----
#pragma unroll
    for (int r = 0; r < 3; ++r) {
        const int t = tid + 256 * r;
        kl[t] = kp[t];
        vl[t] = vp[t];
    }

    const int i = rt * 64 + lane;            // this lane's query row
    const float q = qs[(size_t)bh * Tc + i]; // coalesced, log2e folded
    // slopes[h] = 2^(-(h+1)/8) (H=64), folded with log2(e)
    const float slope2 = exp2f(-0.125f * (float)(h + 1)) * LOG2E;

    v2f cu2[8];                              // {slope*(2u), slope*(2u+1)}
#pragma unroll
    for (int u = 0; u < 8; ++u) {
        cu2[u].x = slope2 * (float)(2 * u);
        cu2[u].y = slope2 * (float)(2 * u + 1);
    }

    __syncthreads();

    const int j0 = w * (Tc / 4);             // this wave's 192-j quarter
    // ALiBi distant-past skip: chunks entirely below i_min - 28/slope2
    int c0 = 0;
    {
        const int jskip = rt * 64 - (int)(28.f / slope2);
        if (jskip > j0) {
            c0 = (jskip - j0) >> 4;
            if (c0 > 12) c0 = 12;
        }
    }

    const v2f* __restrict__ k2p = (const v2f*)&kl[j0];
    const v2f* __restrict__ v2p = (const v2f*)&vl[j0];
    v2f sum2 = {0.f, 0.f}, acc2 = {0.f, 0.f};
    const v2f q2 = {q, q};

    for (int c = c0; c < 12; ++c) {          // chunks of 16 j (8 packed iters)
        const int jc = j0 + 16 * c;          // wave-uniform
        const float mb = slope2 * (float)(jc - i);
        const v2f mb2 = {mb, mb};
        if (jc >= rt * 64 + 64) {
            // FUTURE: all j > all i -> bias = 0 (min(j-i,0)=0)
#pragma unroll
            for (int u = 0; u < 8; ++u) {
                v2f k2 = k2p[8 * c + u];     // ds_read_b64 broadcast
                v2f v2 = v2p[8 * c + u];
                v2f sc = q2 * k2;            // v_pk_mul_f32
                v2f e;
                e.x = __builtin_amdgcn_exp2f(sc.x);
                e.y = __builtin_amdgcn_exp2f(sc.y);
                sum2 += e;
                acc2 = e * v2 + acc2;        // v_pk_fma_f32
            }
        } else if (jc + 15 < rt * 64) {
            // PAST: all j < all i -> bias = slope*(j-i) < 0 (no min needed)
#pragma unroll
            for (int u = 0; u < 8; ++u) {
                v2f k2 = k2p[8 * c + u];
                v2f v2 = v2p[8 * c + u];
                v2f bias = mb2 + cu2[u];     // v_pk_add_f32
                v2f sc = q2 * k2 + bias;     // v_pk_fma_f32
                v2f e;
                e.x = __builtin_amdgcn_exp2f(sc.x);
                e.y = __builtin_amdgcn_exp2f(sc.y);
                sum2 += e;
                acc2 = e * v2 + acc2;
            }
        } else {
            // MIXED (diagonal band, <=5 chunks): full path with min
#pragma unroll
            for (int u = 0; u < 8; ++u) {
                v2f k2 = k2p[8 * c + u];
                v2f v2 = v2p[8 * c + u];
                v2f t2 = mb2 + cu2[u];
                v2f bias;
                bias.x = fminf(t2.x, 0.f);
                bias.y = fminf(t2.y, 0.f);
                v2f sc = q2 * k2 + bias;
                v2f e;
                e.x = __builtin_amdgcn_exp2f(sc.x);
                e.y = __builtin_amdgcn_exp2f(sc.y);
                sum2 += e;
                acc2 = e * v2 + acc2;
            }
        }
    }
    psum[w][lane] = sum2.x + sum2.y;
    pacc[w][lane] = acc2.x + acc2.y;
    __syncthreads();

    // ---- combine 4 j-quarters, write out ----
    if (tid < 64) {
        float s = psum[0][lane] + psum[1][lane] + psum[2][lane] + psum[3][lane];
        float a = pacc[0][lane] + pacc[1][lane] + pacc[2][lane] + pacc[3][lane];
        out[((size_t)(b * Tc + rt * 64 + lane)) * 64 + h] =
            a * __builtin_amdgcn_rcpf(s);
    }
}

extern "C" void kernel_launch(void* const* d_in, const int* in_sizes, int n_in,
                              void* d_out, int out_size, void* d_ws, size_t ws_size,
                              hipStream_t stream) {
    const float* x    = (const float*)d_in[0];
    const float* W    = (const float*)d_in[1];
    const float* vtmp = (const float*)d_in[2];
    const float* ptmp = (const float*)d_in[3];
    float* out = (float*)d_out;

    float* qsl = (float*)d_ws;
    float* ksl = qsl + SLAB;
    float* vsl = ksl + SLAB;

    proj_kernel<<<dim3(24, 16), 256, 0, stream>>>(x, W, vtmp, ptmp, qsl, ksl, vsl);
    attn_kernel<<<dim3(12, Hc, Bc), 256, 0, stream>>>(qsl, ksl, vsl, out);
}

// Round 13
// 75.393 us; speedup vs baseline: 1.3128x; 1.0051x over previous
//
#include <hip/hip_runtime.h>
#include <stdint.h>

// Problem: B,T,C = 2,768,64; N_HEAD=64 -> head_dim=1; fp32 buffers.
// R12 post-mortem: attn wall was the per-CU DS pipe (24 waves x ~80 iters x
// 2 ds_read_b64 ~= 27k cyc/CU ~= 11 us), not VALU. R10's wall was VALU at
// 12 waves/CU. Every LDS-broadcast structure saturates DS before VALU.
// R13: k[j]/v[j] are wave-uniform -> read via UNIFORM SCALAR LOADS
// (s_load_dwordx16, SMEM pipe, previously idle): 24 s_loads/wave replace
// ~160 DS ops. SGPR pairs feed v_pk_fma directly (1 SGPR read/instr).
// No kv LDS staging at all (only the 2KB partial combine remains).
constexpr int Tc = 768;
constexpr int Hc = 64;
constexpr int Bc = 2;
constexpr float LOG2E = 1.44269504088896f;
constexpr size_t SLAB = (size_t)Bc * Hc * Tc;   // 98304 floats per slab

typedef float v2f __attribute__((ext_vector_type(2)));
typedef float v4f __attribute__((ext_vector_type(4)));

// ---------------------------------------------------------------------------
// Kernel 1: projection into transposed slabs (measured ~3 us, R7).
// ---------------------------------------------------------------------------
__global__ __launch_bounds__(256) void proj_kernel(
    const float* __restrict__ x, const float* __restrict__ W,
    const float* __restrict__ vtmp, const float* __restrict__ ptmp,
    float* __restrict__ qs, float* __restrict__ ks, float* __restrict__ vs)
{
    const int lane = threadIdx.x & 63;
    const int w    = __builtin_amdgcn_readfirstlane(threadIdx.x >> 6);
    const int g    = blockIdx.x * 64 + lane;     // global row in [0,1536)
    const int bh0  = (g / Tc) * Hc;              // b*64 (64 | 768: no straddle)
    const int t    = g % Tc;
    const int h    = blockIdx.y * 4 + w;         // wave-uniform head

    float xr[64];
    const v4f* xp = (const v4f*)(x + (size_t)g * 64);
#pragma unroll
    for (int c = 0; c < 16; ++c) ((v4f*)xr)[c] = xp[c];

    const float* __restrict__ wq = W + h * 64;
    const float* __restrict__ wk = W + (64 + h) * 64;
    float aq = 0.f, ak = 0.f;
#pragma unroll
    for (int c = 0; c < 64; ++c) {               // constant indices only
        aq = fmaf(xr[c], wq[c], aq);
        ak = fmaf(xr[c], wk[c], ak);
    }
    const size_t o = (size_t)(bh0 + h) * Tc + t;   // lane-coalesced
    qs[o] = aq * LOG2E;
    ks[o] = ak;
    vs[o] = x[(size_t)g * 64 + h] * vtmp[h] * ptmp[h];   // global reload, not xr[h]
}

// ---------------------------------------------------------------------------
// Kernel 2: attention. Block = (rt: 64 rows, h, b); lane = row; 4 waves = 4
// j-quarters (192 j). Per 16-j chunk: k[16], v[16] via uniform scalar loads
// (SGPRs, SMEM pipe); 8 packed iters: v_pk ops with SGPR-pair k/v operands +
// 2 exp2. Wave-uniform chunk classes: [skip] | past (no min) | mixed (full)
// | future (bias=0). grid (12,64,2) = 1536 = 6 blocks/CU, 24 waves/CU.
// ---------------------------------------------------------------------------
__global__ __launch_bounds__(256, 6) void attn_kernel(
    const float* __restrict__ qs, const float* __restrict__ ks,
    const float* __restrict__ vs, float* __restrict__ out)
{
    const int tid  = threadIdx.x;
    const int lane = tid & 63;
    const int w    = __builtin_amdgcn_readfirstlane(tid >> 6);
    const int rt   = blockIdx.x;   // 0..11 (64-row tile)
    const int h    = blockIdx.y;
    const int b    = blockIdx.z;
    const int bh   = b * Hc + h;

    __shared__ float psum[4][64], pacc[4][64];   // 2 KB only

    const float* __restrict__ kp = ks + (size_t)bh * Tc;
    const float* __restrict__ vp = vs + (size_t)bh * Tc;

    const int i = rt * 64 + lane;            // this lane's query row
    const float q = qs[(size_t)bh * Tc + i]; // coalesced, log2e folded
    // slopes[h] = 2^(-(h+1)/8) (H=64), folded with log2(e)
    const float slope2 = exp2f(-0.125f * (float)(h + 1)) * LOG2E;

    v2f cu2[8];                              // {slope*(2u), slope*(2u+1)}
#pragma unroll
    for (int u = 0; u < 8; ++u) {
        cu2[u].x = slope2 * (float)(2 * u);
        cu2[u].y = slope2 * (float)(2 * u + 1);
    }

    const int j0 = w * (Tc / 4);             // this wave's 192-j quarter
    // ALiBi distant-past skip: chunks entirely below i_min - 28/slope2
    int c0 = 0;
    {
        const int jskip = rt * 64 - (int)(28.f / slope2);
        if (jskip > j0) {
            c0 = (jskip - j0) >> 4;
            if (c0 > 12) c0 = 12;
        }
    }

    v2f sum2 = {0.f, 0.f}, acc2 = {0.f, 0.f};
    const v2f q2 = {q, q};

    for (int c = c0; c < 12; ++c) {          // chunks of 16 j (8 packed iters)
        const int jc = j0 + 16 * c;          // wave-uniform
        // Uniform scalar loads: expect 2x s_load_dwordx16 (SMEM pipe, SGPRs).
        float kk[16], vv[16];
        const float* __restrict__ kc = kp + jc;
        const float* __restrict__ vc = vp + jc;
#pragma unroll
        for (int u = 0; u < 16; ++u) { kk[u] = kc[u]; vv[u] = vc[u]; }

        const float mb = slope2 * (float)(jc - i);
        const v2f mb2 = {mb, mb};
        if (jc >= rt * 64 + 64) {
            // FUTURE: all j > all i -> bias = 0
#pragma unroll
            for (int u = 0; u < 8; ++u) {
                v2f k2 = {kk[2 * u], kk[2 * u + 1]};   // SGPR pair
                v2f v2 = {vv[2 * u], vv[2 * u + 1]};
                v2f sc = q2 * k2;            // v_pk_mul_f32
                v2f e;
                e.x = __builtin_amdgcn_exp2f(sc.x);
                e.y = __builtin_amdgcn_exp2f(sc.y);
                sum2 += e;
                acc2 = e * v2 + acc2;        // v_pk_fma_f32
            }
        } else if (jc + 15 < rt * 64) {
            // PAST: all j < all i -> bias = slope*(j-i) (no min)
#pragma unroll
            for (int u = 0; u < 8; ++u) {
                v2f k2 = {kk[2 * u], kk[2 * u + 1]};
                v2f v2 = {vv[2 * u], vv[2 * u + 1]};
                v2f bias = mb2 + cu2[u];
                v2f sc = q2 * k2 + bias;
                v2f e;
                e.x = __builtin_amdgcn_exp2f(sc.x);
                e.y = __builtin_amdgcn_exp2f(sc.y);
                sum2 += e;
                acc2 = e * v2 + acc2;
            }
        } else {
            // MIXED (diagonal band): full path with min
#pragma unroll
            for (int u = 0; u < 8; ++u) {
                v2f k2 = {kk[2 * u], kk[2 * u + 1]};
                v2f v2 = {vv[2 * u], vv[2 * u + 1]};
                v2f t2 = mb2 + cu2[u];
                v2f bias;
                bias.x = fminf(t2.x, 0.f);
                bias.y = fminf(t2.y, 0.f);
                v2f sc = q2 * k2 + bias;
                v2f e;
                e.x = __builtin_amdgcn_exp2f(sc.x);
                e.y = __builtin_amdgcn_exp2f(sc.y);
                sum2 += e;
                acc2 = e * v2 + acc2;
            }
        }
    }
    psum[w][lane] = sum2.x + sum2.y;
    pacc[w][lane] = acc2.x + acc2.y;
    __syncthreads();

    // ---- combine 4 j-quarters, write out ----
    if (tid < 64) {
        float s = psum[0][lane] + psum[1][lane] + psum[2][lane] + psum[3][lane];
        float a = pacc[0][lane] + pacc[1][lane] + pacc[2][lane] + pacc[3][lane];
        out[((size_t)(b * Tc + rt * 64 + lane)) * 64 + h] =
            a * __builtin_amdgcn_rcpf(s);
    }
}

extern "C" void kernel_launch(void* const* d_in, const int* in_sizes, int n_in,
                              void* d_out, int out_size, void* d_ws, size_t ws_size,
                              hipStream_t stream) {
    const float* x    = (const float*)d_in[0];
    const float* W    = (const float*)d_in[1];
    const float* vtmp = (const float*)d_in[2];
    const float* ptmp = (const float*)d_in[3];
    float* out = (float*)d_out;

    float* qsl = (float*)d_ws;
    float* ksl = qsl + SLAB;
    float* vsl = ksl + SLAB;

    proj_kernel<<<dim3(24, 16), 256, 0, stream>>>(x, W, vtmp, ptmp, qsl, ksl, vsl);
    attn_kernel<<<dim3(12, Hc, Bc), 256, 0, stream>>>(qsl, ksl, vsl, out);
}